// Round 3
// baseline (148.614 us; speedup 1.0000x reference)
//
#include <hip/hip_runtime.h>
#include <hip/hip_bf16.h>
#include <math.h>

// ---------------------------------------------------------------------------
// CgpHmmCell forward: 512 seqs x 2048 steps x 25-state HMM (23 live states).
//
// ROUND-19 = SCALAR-PIPE EMISSION FETCH (wave-per-chunk, SMEM rows).
// R12 wall: 96 broadcast ds_read_b128/CU-round x ~12cyc = 1152 cyc. Broadcast
// of wave-uniform data through the DS return bus is the waste. R17/R18 proved
// the VMEM pipe can't be co-scheduled (fixed per-step drain cost: 48 vs 32
// VMEM insts/round -> identical 82-84us).
// R19: wave = ONE chunk (64 lanes, 23 live) -> row address is WAVE-UNIFORM ->
// fetch the whole 96B row with 3x s_load_dwordx8 (SMEM/K$ pipe, 9.6KB table
// K$-resident), consume directly as SGPR operands in the pk-fp32 step (1 SGPR
// per VALU op: legal). Scan DS insts = ZERO. Cost: 1024 thr, lanes 23..63
// idle -> VALU rounds ~8 waves/SIMD x ~65cyc = 520 cyc, still 2.4x below the
// DS wall. SMEM is OOO -> lgkmcnt(0) only; step order {wait(cur), issue(next),
// compute(cur)} so the wait never drains the just-issued load; residual
// latency hidden by 8-wave TLP. Rows stored in step-consumption slot order so
// SGPR pairs feed v_pk_* directly. Chunk decomposition (16x128) and all
// arithmetic bit-identical to R12 -> absmax 0.0 preserved.
//
// HARD RULES: never pass __launch_bounds__ min-waves (R4/R14); keep distance-1
// token prefetch (R6); never trade 1 LDS inst for >1 VALU inst (R8/R13);
// renorm-16 with x16 prescale (R11); VMEM emission fetch is a dead end
// (R17/R18: fixed drain cost, not throughput).
// ---------------------------------------------------------------------------

typedef float v2f __attribute__((ext_vector_type(2)));
typedef float v8f __attribute__((ext_vector_type(8)));

#define NSTATES 25
#define NLIVE   23
#define NFLAT   216
#define NPACK   100
#define TLEN    2048
#define NSEQ    512
#define CHUNKS  16
#define CLEN    128

#define LOG16 2.772588722239781f

#define RFL(x) __builtin_amdgcn_readfirstlane(x)

// pos -> canonical state (pad slot = 23, dead)
__device__ __constant__ int PERMC[24] = {1,4,2,5,3,6,7,10,8,11,9,12,
                                         14,17,15,18,16,19,20,0,21,13,22,23};
// canonical state -> position (live states only)
__device__ __constant__ int POSA[NLIVE] = {19,0,2,4,1,3,5,6,8,10,7,9,11,21,
                                           12,14,16,13,15,17,18,20,22};
// permuted-position -> storage slot within a 24-float row (pair-friendly
// order so SGPR pairs feed v_pk_* directly)
__device__ __constant__ int SLOTP[24] = {12,13,0,1,2,3,14,15,4,5,6,7,
                                         16,17,8,9,10,11,18,19,20,21,22,23};

// packed emission table, 100 rows x 24 floats (96B rows), read via s_load
__device__ __align__(16) float gBt[NPACK * 24];

// ---------------------------------------------------------------------------
// Compile-time emission map (validated: absmax 0.0 across rounds).
// ---------------------------------------------------------------------------
struct WMap { short m[NSTATES * NFLAT]; };

constexpr WMap make_wmap() {
  WMap w{};
  for (int i = 0; i < NSTATES * NFLAT; i++) w.m[i] = -2;
  const unsigned char ST[29] = {0,1,2,3,4,5,6,7,8,9,10,11,11,12,12,12,13,
                                14,15,16,17,18,19,20,21,22,23,23,24};
  const unsigned char M1[29] = {0x1F,0x1F,0x1F,0x11,0x18,0x14,0x1F,0x1F,0x1F,
                                0x1F,0x0F,0x0F,0x0F,0x08,0x08,0x08,0x0F,
                                0x1F,0x1F,0x1F,0x1F,0x1F,0x1F,0x1F,0x1F,0x1F,
                                0x0F,0x0F,0x20};
  const unsigned char M2[29] = {0x1F,0x1F,0x11,0x18,0x14,0x1F,0x1F,0x1F,0x1F,
                                0x1F,0x0F,0x08,0x08,0x01,0x01,0x04,0x0F,
                                0x1F,0x1F,0x1F,0x1F,0x1F,0x1F,0x1F,0x1F,0x1F,
                                0x0F,0x20,0x20};
  const unsigned char M3[29] = {0x0F,0x01,0x08,0x04,0x0F,0x0F,0x0F,0x0F,0x0F,
                                0x0F,0x08,0x01,0x04,0x01,0x04,0x01,0x0F,
                                0x0F,0x0F,0x0F,0x0F,0x0F,0x0F,0x0F,0x0F,0x0F,
                                0x20,0x20,0x20};
  const unsigned char TR[29] = {1,1,1,0,1,1,1,1,1,1,1,1,1,0,0,0,1,
                                1,1,1,1,1,1,1,1,1,1,1,0};
  int k = 0;
  for (int s = 0; s < 29; s++) {
    for (int c1 = 0; c1 < 6; c1++) {
      if (!((M1[s] >> c1) & 1)) continue;
      for (int c2 = 0; c2 < 6; c2++) {
        if (!((M2[s] >> c2) & 1)) continue;
        if (c1 != 4 && c2 == 4) continue;
        for (int c3 = 0; c3 < 6; c3++) {
          if (!((M3[s] >> c3) & 1)) continue;
          w.m[ST[s] * NFLAT + c1 * 36 + c2 * 6 + c3] =
              TR[s] ? (short)(k++) : (short)-1;
        }
      }
    }
  }
  return w;
}
__device__ __constant__ WMap WMAP = make_wmap();

__device__ __forceinline__ unsigned short f2bf(float x) {  // RNE
  unsigned int u = __float_as_uint(x);
  u += 0x7fffu + ((u >> 16) & 1u);
  return (unsigned short)(u >> 16);
}

struct Wp {
  v2f w01, wA, wB, wC, wD, wE, wF;
  float w4, w5, w8, w11;
};

// ---------------------------------------------------------------------------
// One HMM step, permuted-pair layout, emission row in SGPRs (A0/A1/A2 = the
// three dwordx8 blocks). Slot order (position labels match R12's F comps):
//   A0 = p{2,3,4,5,8,9,10,11}   A1 = p{14,15,16,17,0,1,6,7}
//   A2 = p{12,13,18,19,20,21,22,pad}
// Same multiplies, same values as validated R12 step_pk (absmax 0.0).
// ---------------------------------------------------------------------------
__device__ __forceinline__ void step_pk_s(v2f (&Q)[12], const v8f& A0,
                                          const v8f& A1, const v8f& A2,
                                          const Wp& W) {
  float a0 = Q[9].y,  a3 = Q[2].x,  a6 = Q[2].y,  a9 = Q[5].x;
  float a12 = Q[5].y, a13 = Q[10].y, a16 = Q[8].x, a19 = Q[8].y, a22 = Q[11].x;
  float q9x = Q[9].x, q10x = Q[10].x;   // old a20, a21

  v2f t01 = a0 * W.w01;                  // (n0, n1)
  v2f t44 = a3 * W.wA + a16 * W.wB;      // (n4, n14)
  v2f t77 = a6 * W.wC + a19 * W.wD;      // (n7 partial, n17)
  float n7  = fmaf(a3, W.w4, t77.x);
  v2f tAA = a9 * W.wE + a22 * W.wF;      // (n10 partial, n20)
  float n10 = fmaf(a3, W.w5, fmaf(a6, W.w8, tAA.x));
  float n13 = fmaf(a13, W.w11, a12);

  // aligned shift pairs (transition weight 1.0) * emission pair
  v2f nQ1 = Q[0] * (v2f){A0[0], A0[1]};  // (p2,p3)
  v2f nQ2 = Q[1] * (v2f){A0[2], A0[3]};  // (p4,p5)
  v2f nQ4 = Q[3] * (v2f){A0[4], A0[5]};  // (p8,p9)
  v2f nQ5 = Q[4] * (v2f){A0[6], A0[7]};  // (p10,p11)
  v2f nQ7 = Q[6] * (v2f){A1[0], A1[1]};  // (p14,p15)
  v2f nQ8 = Q[7] * (v2f){A1[2], A1[3]};  // (p16,p17)

  Q[0]  = (v2f){t01.y, t44.x} * (v2f){A1[4], A1[5]};  // (p0,p1)
  Q[3]  = (v2f){n7,    n10  } * (v2f){A1[6], A1[7]};  // (p6,p7)
  Q[6]  = (v2f){t44.y, t77.y} * (v2f){A2[0], A2[1]};  // (p12,p13)
  Q[9]  = (v2f){tAA.y, t01.x} * (v2f){A2[2], A2[3]};  // (p18,p19)
  Q[10] = (v2f){q9x,   n13  } * (v2f){A2[4], A2[5]};  // (p20,p21)
  Q[11].x = q10x * A2[6];                             // p22 (pad .y stays)
  Q[1] = nQ1; Q[2] = nQ2; Q[4] = nQ4; Q[5] = nQ5; Q[7] = nQ7; Q[8] = nQ8;
}

__device__ __forceinline__ void renorm_pk(v2f (&Q)[12], float& L) {
  v2f acc = ((Q[0] + Q[1]) + (Q[2] + Q[3])) + ((Q[4] + Q[5]) + (Q[6] + Q[7]))
          + ((Q[8] + Q[9]) + (Q[10] + Q[11]));
  float s = acc.x + acc.y;
  if (s > 0.0f) {
    L += __logf(s);
    float r = __fdividef(1.0f, s);
    #pragma unroll
    for (int k = 0; k < 12; k++) Q[k] *= r;
  } else {
    L = -3.0e38f;  // row died; stays dead
  }
}

// Issue the 96B row for the step whose token is nt_ (3x s_load_dwordx8 on the
// SMEM pipe). Early-clobber outputs; address math is a uniform SALU chain.
#define ISSUE_ROW(R0, R1, R2, nt_) { int nt = (nt_); \
  unsigned long long p_ = gb + (unsigned long long)((((c12 << 2) + nt) * 96)); \
  asm volatile("s_load_dwordx8 %0, %3, 0x0\n\t" \
               "s_load_dwordx8 %1, %3, 0x20\n\t" \
               "s_load_dwordx8 %2, %3, 0x40" \
               : "=&s"(R0), "=&s"(R1), "=&s"(R2) : "s"(p_)); \
  c12 = p2 * 5 + nt; p2 = nt; }

// Wait for the in-flight row; ties the values so consumers are SSA-ordered
// after the wait (SMEM completes OOO -> lgkmcnt(0) only; no LDS in the scan).
#define ROWWAIT(R0, R1, R2) \
  asm volatile("s_waitcnt lgkmcnt(0)" : "+s"(R0), "+s"(R1), "+s"(R2))

// One step: wait current row -> issue next row -> compute current step.
#define SSTEP(C0, C1, C2, N0, N1, N2, nt_) { \
  ROWWAIT(C0, C1, C2); \
  ISSUE_ROW(N0, N1, N2, nt_); \
  step_pk_s(Q, C0, C1, C2, W); }

// ---------------------------------------------------------------------------
// Prep kernel: build gBt bit-identically to the validated build (same strided
// sum + shfl tree, same expf path), stored in slot order. Block = state.
// ---------------------------------------------------------------------------
__global__ __launch_bounds__(32)
void prep_kernel(const float* __restrict__ wE) {
  const int st  = blockIdx.x;     // 0..22
  const int row = threadIdx.x;    // 0..31
  const int pos = POSA[st];
  const int slot = SLOTP[pos];
  float part = 0.0f;
  for (int c = row; c < NFLAT; c += 32) {
    short m = WMAP.m[st * NFLAT + c];
    if (m == -1) part += expf(1.0f);
    else if (m >= 0) part += expf(wE[m]);
  }
  #pragma unroll
  for (int m = 1; m < 32; m <<= 1) part += __shfl_xor(part, m, 32);
  float inv = 16.0f / part;
  for (int i = row; i < NPACK; i += 32) {
    int c12 = i >> 2, nt = i & 3;
    int p1 = c12 / 5, p2v = c12 - 5 * p1;
    int flat = p1 * 36 + p2v * 6 + nt;
    short m = WMAP.m[st * NFLAT + flat];
    float v = 0.0f;
    if (m == -1) v = expf(1.0f);
    else if (m >= 0) v = expf(wE[m]);
    gBt[i * 24 + slot] = v * inv;
  }
  if (st == 0) {  // pad slot 23: keep clean for all rows
    for (int i = row; i < NPACK; i += 32) gBt[i * 24 + 23] = 0.0f;
  }
}

// ---------------------------------------------------------------------------
// Main kernel: block = sequence, 1024 thr = 16 waves, wave = chunk (CLEN=128).
// ---------------------------------------------------------------------------
__global__ __launch_bounds__(1024)
void hmm_kernel(const float* __restrict__ wT, const float* __restrict__ wE,
                const float* __restrict__ wI, const int* __restrict__ tokens,
                float* __restrict__ out) {
  __shared__ __align__(16) unsigned short sT[CHUNKS * NLIVE * 24];  // 17664 B
  __shared__ float sL[CHUNKS * NLIVE];                              //  1472 B
  __shared__ float sAW[24];
  __shared__ float sI[32];

  const int tid   = threadIdx.x;
  const int seq   = blockIdx.x;
  const int lane  = tid & 63;
  const int chunk = RFL(tid >> 6);        // wave id = chunk, uniform
  const int* trow = tokens + (size_t)seq * TLEN;

  if (tid == 480) {
    // softmax of multi-entry A rows -> 21 packed weights (validated)
    const float w0 = wT[0], w1 = wT[1], w2 = wT[2], w3 = wT[3], w4 = wT[4];
    const float w5 = wT[5], w6 = wT[6], w7 = wT[7], w8 = wT[8], w9 = wT[9];
    { float e0 = expf(1.0f - w0), e1 = expf(w0), is = 1.0f / (e0 + e1);
      sAW[0] = e0 * is; sAW[1] = e1 * is; }
    { float e4 = expf(w1), e14 = expf(w3);
      float e7 = expf(1.0f - w9 * w9), e10 = expf(1.0f - w9 * w9 * w9);
      float is = 1.0f / (e4 + e14 + e7 + e10);
      sAW[2] = e4 * is;  sAW[3] = e14 * is;
      sAW[4] = e7 * is;  sAW[5] = e10 * is; }
    { float e7 = expf(w2), e17 = expf(w4), e10 = expf(1.0f - w9 * w9);
      float is = 1.0f / (e7 + e17 + e10);
      sAW[6] = e7 * is; sAW[7] = e17 * is; sAW[8] = e10 * is; }
    { float e20 = expf(w5), e10 = expf(1.0f - w5), is = 1.0f / (e20 + e10);
      sAW[9] = e20 * is; sAW[10] = e10 * is; }
    sAW[11] = 0.5f; sAW[12] = 0.5f;   // row 13
    { float e4 = expf(w6), e14 = expf(1.0f - w6), is = 1.0f / (e4 + e14);
      sAW[13] = e4 * is; sAW[14] = e14 * is; }
    { float e7 = expf(w7), e17 = expf(1.0f - w7), is = 1.0f / (e7 + e17);
      sAW[15] = e7 * is; sAW[16] = e17 * is; }
    { float e10 = expf(w8), e20 = expf(1.0f - w8), is = 1.0f / (e10 + e20);
      sAW[17] = e10 * is; sAW[18] = e20 * is; }
    sAW[19] = 0.5f; sAW[20] = 0.5f;
  } else if (tid == 481) {
    float e[9], s = 0.0f;
    for (int i = 0; i < 9; i++) { e[i] = expf(wI[i]); s += e[i]; }
    float inv = 1.0f / s;
    for (int i = 0; i < 9; i++) sI[i] = e[i] * inv;
    for (int i = 9; i < 32; i++) sI[i] = 0.0f;
  }
  __syncthreads();

  // A-weights: wave-uniform -> SGPRs, then packed pairs
  float w[21];
  #pragma unroll
  for (int i = 0; i < 21; i++)
    w[i] = __uint_as_float(
        (unsigned)__builtin_amdgcn_readfirstlane(__float_as_uint(sAW[i])));
  Wp W;
  W.w01 = (v2f){w[0],  w[1]};
  W.wA  = (v2f){w[2],  w[3]};
  W.wB  = (v2f){w[13], w[14]};
  W.wC  = (v2f){w[6],  w[7]};
  W.wD  = (v2f){w[15], w[16]};
  W.wE  = (v2f){w[10], w[9]};
  W.wF  = (v2f){w[17], w[18]};
  W.w4 = w[4]; W.w5 = w[5]; W.w8 = w[8]; W.w11 = w[11];

  // ---- scan (no LDS ops inside: lgkmcnt counts SMEM only) ----
  const int t0 = chunk * CLEN;
  const unsigned long long gb = (unsigned long long)(const void*)gBt;

  v2f Q[12];
  #pragma unroll
  for (int k = 0; k < 12; k++) {
    Q[k].x = (lane == PERMC[2 * k]) ? 1.0f : 0.0f;
    Q[k].y = (lane == PERMC[2 * k + 1]) ? 1.0f : 0.0f;
  }
  float L = 0.0f;

  v8f A0, A1, A2, B0, B1, B2;
  int c12, p2;
  int4 q0 = *(const int4*)(trow + t0);
  int4 q1 = *(const int4*)(trow + t0 + 4);

  int b;
  if (chunk == 0) {
    // body 0 = steps t = 1..7 (t = 0 folded into the combine's init)
    int s0 = RFL(q0.x), s1 = RFL(q0.y), s2 = RFL(q0.z), s3 = RFL(q0.w);
    int s4 = RFL(q1.x), s5 = RFL(q1.y), s6 = RFL(q1.z), s7 = RFL(q1.w);
    int4 nq0 = *(const int4*)(trow + 8);
    int4 nq1 = *(const int4*)(trow + 12);
    int sn0 = RFL(nq0.x);
    c12 = 20 + s0; p2 = s0;
    ISSUE_ROW(B0, B1, B2, s1);               // row t=1 -> B
    SSTEP(B0, B1, B2, A0, A1, A2, s2);       // t=1
    SSTEP(A0, A1, A2, B0, B1, B2, s3);       // t=2
    SSTEP(B0, B1, B2, A0, A1, A2, s4);       // t=3
    SSTEP(A0, A1, A2, B0, B1, B2, s5);       // t=4
    SSTEP(B0, B1, B2, A0, A1, A2, s6);       // t=5
    SSTEP(A0, A1, A2, B0, B1, B2, s7);       // t=6
    SSTEP(B0, B1, B2, A0, A1, A2, sn0);      // t=7, issue row t=8 -> A
    b = 1;
    q0 = nq0; q1 = nq1;
  } else {
    int2 pp = *(const int2*)(trow + t0 - 2);
    int sp0 = RFL(pp.x), sp1 = RFL(pp.y);
    int s0 = RFL(q0.x);
    c12 = sp0 * 5 + sp1; p2 = sp1;
    ISSUE_ROW(A0, A1, A2, s0);               // row for s0 -> A
    b = 0;
  }

  for (; b < CLEN / 8 - 1; b++) {
    int4 n0 = *(const int4*)(trow + t0 + (b + 1) * 8);        // distance-1
    int4 n1 = *(const int4*)(trow + t0 + (b + 1) * 8 + 4);    // token prefetch
    int s1 = RFL(q0.y), s2 = RFL(q0.z), s3 = RFL(q0.w);
    int s4 = RFL(q1.x), s5 = RFL(q1.y), s6 = RFL(q1.z), s7 = RFL(q1.w);
    int sn0 = RFL(n0.x);
    SSTEP(A0, A1, A2, B0, B1, B2, s1);   // s0
    SSTEP(B0, B1, B2, A0, A1, A2, s2);   // s1
    SSTEP(A0, A1, A2, B0, B1, B2, s3);   // s2
    SSTEP(B0, B1, B2, A0, A1, A2, s4);   // s3
    SSTEP(A0, A1, A2, B0, B1, B2, s5);   // s4
    SSTEP(B0, B1, B2, A0, A1, A2, s6);   // s5
    SSTEP(A0, A1, A2, B0, B1, B2, s7);   // s6
    SSTEP(B0, B1, B2, A0, A1, A2, sn0);  // s7, issue next-body s0 -> A
    if (b & 1) renorm_pk(Q, L);          // every 16 steps (x16 prescale)
    q0 = n0; q1 = n1;
  }
  {
    // tail body: steps s0..s6 issue as usual; s7 waits + computes only
    // (no trailing in-flight s_load past the scan).
    int s1 = RFL(q0.y), s2 = RFL(q0.z), s3 = RFL(q0.w);
    int s4 = RFL(q1.x), s5 = RFL(q1.y), s6 = RFL(q1.z), s7 = RFL(q1.w);
    SSTEP(A0, A1, A2, B0, B1, B2, s1);   // s0
    SSTEP(B0, B1, B2, A0, A1, A2, s2);   // s1
    SSTEP(A0, A1, A2, B0, B1, B2, s3);   // s2
    SSTEP(B0, B1, B2, A0, A1, A2, s4);   // s3
    SSTEP(A0, A1, A2, B0, B1, B2, s5);   // s4
    SSTEP(B0, B1, B2, A0, A1, A2, s6);   // s5
    SSTEP(A0, A1, A2, B0, B1, B2, s7);   // s6
    ROWWAIT(B0, B1, B2);
    step_pk_s(Q, B0, B1, B2, W);         // s7
    renorm_pk(Q, L);                     // tail b = 15 (odd) -> renorm
  }

  // undo the x16 prescale exactly: chunk 0 ran 127 steps, others 128
  if (L > -1.0e38f) L -= (chunk == 0 ? 127.0f : 128.0f) * LOG16;

  // stash chunk matrix row (bf16, PERMUTED position order) + fp32 L
  if (lane < NLIVE) {
    const int base = (chunk * NLIVE + lane) * 24;
    #pragma unroll
    for (int k = 0; k < 12; k++) {
      ushort2 p; p.x = f2bf(Q[k].x); p.y = f2bf(Q[k].y);
      *(ushort2*)&sT[base + 2 * k] = p;
    }
    sL[chunk * NLIVE + lane] = L;
  }
  __syncthreads();

  // ---- combine (wave 0): fold 16 chunk matrices; lane j = canonical col ----
  if (tid < 64) {
    const int lane0 = tid;
    const bool act = (lane0 < NLIVE);

    int jp = 23;                          // lane's PERMUTED position
    #pragma unroll
    for (int pos = 0; pos < 23; pos++)
      if (PERMC[pos] == lane0) jp = pos;

    const int tok0 = trow[0];
    const int idx0 = 96 + tok0;           // packed (4,4,tok0)

    float v = act ? sI[lane0] * gBt[idx0 * 24 + SLOTP[jp]] : 0.0f;
    float s = v;
    #pragma unroll
    for (int m = 1; m < 32; m <<= 1) s += __shfl_xor(s, m, 32);
    float ll = __logf(s) - LOG16;         // undo prescale on step 0
    v = act ? v * __fdividef(1.0f, s) : 0.0f;

    for (int c = 0; c < CHUNKS; c++) {
      float Lj  = act ? sL[c * NLIVE + lane0] : -3.0e38f;
      float key = (act && v > 0.0f) ? Lj : -3.0e38f;
      float mx = key;
      #pragma unroll
      for (int m = 1; m < 32; m <<= 1) mx = fmaxf(mx, __shfl_xor(mx, m, 32));
      float wgt = (act && v > 0.0f) ? v * __expf(Lj - mx) : 0.0f;

      float nv = 0.0f;
      #pragma unroll
      for (int r = 0; r < NLIVE; r++) {
        float wr = __shfl(wgt, r, 64);
        nv += wr * __uint_as_float(((unsigned)sT[(c * NLIVE + r) * 24 + jp]) << 16);
      }
      float nva = act ? nv : 0.0f;
      float s2 = nva;
      #pragma unroll
      for (int m = 1; m < 32; m <<= 1) s2 += __shfl_xor(s2, m, 32);
      ll += mx + __logf(s2);
      v = act ? nv * __fdividef(1.0f, s2) : 0.0f;
    }

    if (lane0 == 0) out[seq] = ll;
  }
}

// ---------------------------------------------------------------------------
extern "C" void kernel_launch(void* const* d_in, const int* in_sizes, int n_in,
                              void* d_out, int out_size, void* d_ws, size_t ws_size,
                              hipStream_t stream) {
  const float* wT = (const float*)d_in[0];   // transition_kernel (10)
  const float* wE = (const float*)d_in[1];   // emission_kernel (5400)
  const float* wI = (const float*)d_in[2];   // init_kernel (25)
  const int* tokens = (const int*)d_in[3];   // (512, 2048) int32
  float* out = (float*)d_out;                // (512,) float32
  (void)d_ws; (void)ws_size;                 // workspace unused

  prep_kernel<<<NLIVE, 32, 0, stream>>>(wE);
  hmm_kernel<<<NSEQ, 1024, 0, stream>>>(wT, wE, wI, tokens, out);
}

// Round 4
// 122.175 us; speedup vs baseline: 1.2164x; 1.2164x over previous
//
#include <hip/hip_runtime.h>
#include <hip/hip_bf16.h>
#include <math.h>

// ---------------------------------------------------------------------------
// CgpHmmCell forward: 512 seqs x 2048 steps x 25-state HMM (23 live states).
//
// ROUND-20 = BASIS-PACKED CHUNKS (2 bases/lane, 16 lanes/chunk, 4 chunks/wave).
// R12's wall: DS return bus, 6 ds_read_b128/wave-step (96B/lane/step is the
// per-lane minimum when lane = 1 basis). R17/R18 (VMEM) and R19 (SMEM) all
// regressed: alternate fetch pipes serialize per-step; falsified.
// R20 halves DS *per chunk-step* instead: each lane carries TWO basis vectors
// (v2f over bases), chunk = 16 lanes, wave = 4 chunks -> the same 6
// ds_read_b128/wave-step now serve 4 chunk-steps (2x). Numerical path is
// bit-identical to R12: same 16x128 chunk decomposition, same per-basis
// expression trees (same fmaf/contract shapes, renorm-16 tree, bf16 stash,
// combine); only the lane<->basis packing changes. Emission rows repitched to
// 28 floats (112B, 16B-aligned) so 4 distinct rows/instruction avoid bank
// collisions except drow=0 mod 8 (mostly 2-way = free).
// Model: DS 48 inst x 12cyc = 576 cyc/CU-round (was 1152); VALU ~300 cyc.
//
// HARD RULES: never pass __launch_bounds__ min-waves (R4/R14); keep distance-1
// token prefetch (R6); never trade 1 LDS inst for >1 VALU inst (R8/R13);
// renorm-16 with x16 prescale (R11); emission fetch must stay on the DS pipe
// (R17/R18 VMEM, R19 SMEM: all serialize).
// ---------------------------------------------------------------------------

typedef float v2f __attribute__((ext_vector_type(2)));
typedef float v4f __attribute__((ext_vector_type(4)));

#define NSTATES 25
#define NLIVE   23
#define NFLAT   216
#define NPACK   100
#define PITCH   28
#define TLEN    2048
#define NSEQ    512
#define CHUNKS  16
#define CLEN    128

#define LOG16 2.772588722239781f

// pos -> canonical state (pad slot = 23, dead)
__device__ __constant__ int PERMC[24] = {1,4,2,5,3,6,7,10,8,11,9,12,
                                         14,17,15,18,16,19,20,0,21,13,22,23};
// canonical state -> position (live states only)
__device__ __constant__ int POSA[NLIVE] = {19,0,2,4,1,3,5,6,8,10,7,9,11,21,
                                           12,14,16,13,15,17,18,20,22};

// ---------------------------------------------------------------------------
// Compile-time emission map (validated: absmax 0.0 across rounds).
// ---------------------------------------------------------------------------
struct WMap { short m[NSTATES * NFLAT]; };

constexpr WMap make_wmap() {
  WMap w{};
  for (int i = 0; i < NSTATES * NFLAT; i++) w.m[i] = -2;
  const unsigned char ST[29] = {0,1,2,3,4,5,6,7,8,9,10,11,11,12,12,12,13,
                                14,15,16,17,18,19,20,21,22,23,23,24};
  const unsigned char M1[29] = {0x1F,0x1F,0x1F,0x11,0x18,0x14,0x1F,0x1F,0x1F,
                                0x1F,0x0F,0x0F,0x0F,0x08,0x08,0x08,0x0F,
                                0x1F,0x1F,0x1F,0x1F,0x1F,0x1F,0x1F,0x1F,0x1F,
                                0x0F,0x0F,0x20};
  const unsigned char M2[29] = {0x1F,0x1F,0x11,0x18,0x14,0x1F,0x1F,0x1F,0x1F,
                                0x1F,0x0F,0x08,0x08,0x01,0x01,0x04,0x0F,
                                0x1F,0x1F,0x1F,0x1F,0x1F,0x1F,0x1F,0x1F,0x1F,
                                0x0F,0x20,0x20};
  const unsigned char M3[29] = {0x0F,0x01,0x08,0x04,0x0F,0x0F,0x0F,0x0F,0x0F,
                                0x0F,0x08,0x01,0x04,0x01,0x04,0x01,0x0F,
                                0x0F,0x0F,0x0F,0x0F,0x0F,0x0F,0x0F,0x0F,0x0F,
                                0x20,0x20,0x20};
  const unsigned char TR[29] = {1,1,1,0,1,1,1,1,1,1,1,1,1,0,0,0,1,
                                1,1,1,1,1,1,1,1,1,1,1,0};
  int k = 0;
  for (int s = 0; s < 29; s++) {
    for (int c1 = 0; c1 < 6; c1++) {
      if (!((M1[s] >> c1) & 1)) continue;
      for (int c2 = 0; c2 < 6; c2++) {
        if (!((M2[s] >> c2) & 1)) continue;
        if (c1 != 4 && c2 == 4) continue;
        for (int c3 = 0; c3 < 6; c3++) {
          if (!((M3[s] >> c3) & 1)) continue;
          w.m[ST[s] * NFLAT + c1 * 36 + c2 * 6 + c3] =
              TR[s] ? (short)(k++) : (short)-1;
        }
      }
    }
  }
  return w;
}
__device__ __constant__ WMap WMAP = make_wmap();

__device__ __forceinline__ unsigned short f2bf(float x) {  // RNE
  unsigned int u = __float_as_uint(x);
  u += 0x7fffu + ((u >> 16) & 1u);
  return (unsigned short)(u >> 16);
}

// splat weights as v2f (over the 2 bases); scalars for the fmaf edges
struct Wp2 {
  v2f w0, w1, w2, w3, w6, w7, w9, w10, w13, w14, w15, w16, w17, w18;
  float w4, w5, w8, w11;
};

#define SP(x) ((v2f){(x), (x)})
#define FMA2(a, ws, c) ((v2f){fmaf((a).x, (ws), (c).x), \
                              fmaf((a).y, (ws), (c).y)})

// ---------------------------------------------------------------------------
// One HMM step. Q[p] = v2f over (basisA, basisB) at PERMUTED position p
// (p = 0..22; pad p23 dropped — it is identically 0).
// Exact p-indexed transcription of R12's step_pk expression trees:
// same mul/add/fmaf shapes per basis => bit-identical values.
// ---------------------------------------------------------------------------
__device__ __forceinline__ void step_pk2(v2f (&Q)[23], const v4f (&F)[6],
                                         const Wp2& W) {
  v2f o19 = Q[19], o4 = Q[4], o5 = Q[5], o10 = Q[10], o11 = Q[11];
  v2f o21 = Q[21], o16 = Q[16], o17 = Q[17], o22 = Q[22];
  v2f o18 = Q[18], o20 = Q[20];

  v2f n0  = o19 * W.w0;                    // state0 self
  v2f n1  = o19 * W.w1;                    // 0->1
  v2f n4  = o4 * W.w2  + o16 * W.w13;      // ->4
  v2f n14 = o4 * W.w3  + o16 * W.w14;      // ->14
  v2f t77 = o5 * W.w6  + o17 * W.w15;
  v2f n7  = FMA2(o4, W.w4, t77);           // ->7
  v2f n17 = o5 * W.w7  + o17 * W.w16;      // ->17
  v2f tAA = o10 * W.w10 + o22 * W.w17;
  v2f n10 = FMA2(o4, W.w5, FMA2(o5, W.w8, tAA));  // ->10
  v2f n20 = o10 * W.w9 + o22 * W.w18;      // ->20
  v2f n13 = FMA2(o21, W.w11, o11);         // ->13

  // shift pairs (transition weight 1.0) x emission — read olds first
  v2f s2  = Q[0]  * SP(F[0].z),  s3  = Q[1]  * SP(F[0].w);
  v2f s4  = Q[2]  * SP(F[1].x),  s5  = Q[3]  * SP(F[1].y);
  v2f s8  = Q[6]  * SP(F[2].x),  s9  = Q[7]  * SP(F[2].y);
  v2f s10 = Q[8]  * SP(F[2].z),  s11 = Q[9]  * SP(F[2].w);
  v2f s14 = Q[12] * SP(F[3].z),  s15 = Q[13] * SP(F[3].w);
  v2f s16 = Q[14] * SP(F[4].x),  s17 = Q[15] * SP(F[4].y);
  v2f s20 = o18 * SP(F[5].x);    // p20 <- old p18 (state20 -> 21)
  v2f s22 = o20 * SP(F[5].z);    // p22 <- old p20 (state21 -> 22)

  Q[0]  = n1  * SP(F[0].x);
  Q[1]  = n4  * SP(F[0].y);
  Q[6]  = n7  * SP(F[1].z);
  Q[7]  = n10 * SP(F[1].w);
  Q[12] = n14 * SP(F[3].x);
  Q[13] = n17 * SP(F[3].y);
  Q[18] = n20 * SP(F[4].z);
  Q[19] = n0  * SP(F[4].w);
  Q[20] = s20;
  Q[21] = n13 * SP(F[5].y);
  Q[22] = s22;
  Q[2] = s2;  Q[3] = s3;  Q[4] = s4;  Q[5] = s5;
  Q[8] = s8;  Q[9] = s9;  Q[10] = s10; Q[11] = s11;
  Q[14] = s14; Q[15] = s15; Q[16] = s16; Q[17] = s17;
}

// renorm every 16 steps; L = v2f over bases. Same add tree as R12's
// renorm_pk per basis ((even positions) then (odd positions), p23 = 0).
__device__ __forceinline__ void renorm_pk2(v2f (&Q)[23], v2f& L) {
  v2f ax = (((Q[0] + Q[2]) + (Q[4] + Q[6])) +
            ((Q[8] + Q[10]) + (Q[12] + Q[14]))) +
           ((Q[16] + Q[18]) + (Q[20] + Q[22]));
  v2f ay = (((Q[1] + Q[3]) + (Q[5] + Q[7])) +
            ((Q[9] + Q[11]) + (Q[13] + Q[15]))) +
           ((Q[17] + Q[19]) + Q[21]);
  v2f s = ax + ay;
  bool okA = s.x > 0.0f, okB = s.y > 0.0f;
  L.x = okA ? L.x + __logf(s.x) : -3.0e38f;
  L.y = okB ? L.y + __logf(s.y) : -3.0e38f;
  v2f r;
  r.x = okA ? __fdividef(1.0f, s.x) : 1.0f;
  r.y = okB ? __fdividef(1.0f, s.y) : 1.0f;
  #pragma unroll
  for (int k = 0; k < 23; k++) Q[k] *= r;
}

// load fp32 row for NEXT step (6 ds_read_b128, pitch-28), then compute
#define LDROW(F, nt_) { int nt = (nt_); \
  const v4f* er = (const v4f*)(sBt + (((c12 << 2) + nt) * PITCH)); \
  F[0] = er[0]; F[1] = er[1]; F[2] = er[2]; \
  F[3] = er[3]; F[4] = er[4]; F[5] = er[5]; \
  c12 = p2 * 5 + nt; p2 = nt; }
#define LDSTEP(Fn, Fc, nt_) { LDROW(Fn, nt_); step_pk2(Q, Fc, W); }

// ---------------------------------------------------------------------------
// One kernel: block = sequence, 256 thr = 4 waves; chunk = 16-lane group
// (2 bases/lane); 16 chunks x CLEN=128.
// ---------------------------------------------------------------------------
__global__ __launch_bounds__(256)
void hmm_kernel(const float* __restrict__ wT, const float* __restrict__ wE,
                const float* __restrict__ wI, const int* __restrict__ tokens,
                float* __restrict__ out) {
  __shared__ __align__(16) float          sBt[NPACK * PITCH];       // 11200 B
  __shared__ __align__(16) unsigned short sT[CHUNKS * NLIVE * 24];  // 17664 B
  __shared__ float sL[CHUNKS * NLIVE];                              //  1472 B
  __shared__ float sAW[24];
  __shared__ float sI[32];

  const int tid   = threadIdx.x;
  const int seq   = blockIdx.x;
  const int chunk = tid >> 4;          // 0..15 (16-lane groups)
  const int row16 = tid & 15;          // lane within chunk; bases row16,row16+16
  const int* trow = tokens + (size_t)seq * TLEN;

  // ---- per-block setup: fp32 emission rows (x16 prescale), PERMUTED order,
  //      pitch 28. Identical per-state arithmetic to R12 (32-lane strided sum
  //      + shfl tree) -> bit-identical values.
  {
    const int g32 = tid >> 5, r32 = tid & 31;   // 8 groups of 32 lanes
    for (int st = g32; st < NLIVE; st += 8) {
      const int pos = POSA[st];
      float part = 0.0f;
      for (int c = r32; c < NFLAT; c += 32) {
        short m = WMAP.m[st * NFLAT + c];
        if (m == -1) part += expf(1.0f);
        else if (m >= 0) part += expf(wE[m]);
      }
      #pragma unroll
      for (int m = 1; m < 32; m <<= 1) part += __shfl_xor(part, m, 32);
      float inv = 16.0f / part;
      for (int i = r32; i < NPACK; i += 32) {
        int c12 = i >> 2, nt = i & 3;
        int p1 = c12 / 5, p2v = c12 - 5 * p1;
        int flat = p1 * 36 + p2v * 6 + nt;
        short m = WMAP.m[st * NFLAT + flat];
        float v = 0.0f;
        if (m == -1) v = expf(1.0f);
        else if (m >= 0) v = expf(wE[m]);
        sBt[i * PITCH + pos] = v * inv;
      }
    }
  }
  for (int i = tid; i < NPACK; i += 256) sBt[i * PITCH + 23] = 0.0f;  // pad
  if (tid == 224) {
    // softmax of multi-entry A rows -> 21 packed weights (validated)
    const float w0 = wT[0], w1 = wT[1], w2 = wT[2], w3 = wT[3], w4 = wT[4];
    const float w5 = wT[5], w6 = wT[6], w7 = wT[7], w8 = wT[8], w9 = wT[9];
    { float e0 = expf(1.0f - w0), e1 = expf(w0), is = 1.0f / (e0 + e1);
      sAW[0] = e0 * is; sAW[1] = e1 * is; }
    { float e4 = expf(w1), e14 = expf(w3);
      float e7 = expf(1.0f - w9 * w9), e10 = expf(1.0f - w9 * w9 * w9);
      float is = 1.0f / (e4 + e14 + e7 + e10);
      sAW[2] = e4 * is;  sAW[3] = e14 * is;
      sAW[4] = e7 * is;  sAW[5] = e10 * is; }
    { float e7 = expf(w2), e17 = expf(w4), e10 = expf(1.0f - w9 * w9);
      float is = 1.0f / (e7 + e17 + e10);
      sAW[6] = e7 * is; sAW[7] = e17 * is; sAW[8] = e10 * is; }
    { float e20 = expf(w5), e10 = expf(1.0f - w5), is = 1.0f / (e20 + e10);
      sAW[9] = e20 * is; sAW[10] = e10 * is; }
    sAW[11] = 0.5f; sAW[12] = 0.5f;   // row 13
    { float e4 = expf(w6), e14 = expf(1.0f - w6), is = 1.0f / (e4 + e14);
      sAW[13] = e4 * is; sAW[14] = e14 * is; }
    { float e7 = expf(w7), e17 = expf(1.0f - w7), is = 1.0f / (e7 + e17);
      sAW[15] = e7 * is; sAW[16] = e17 * is; }
    { float e10 = expf(w8), e20 = expf(1.0f - w8), is = 1.0f / (e10 + e20);
      sAW[17] = e10 * is; sAW[18] = e20 * is; }
    sAW[19] = 0.5f; sAW[20] = 0.5f;
  } else if (tid == 225) {
    float e[9], s = 0.0f;
    for (int i = 0; i < 9; i++) { e[i] = expf(wI[i]); s += e[i]; }
    float inv = 1.0f / s;
    for (int i = 0; i < 9; i++) sI[i] = e[i] * inv;
    for (int i = 9; i < 32; i++) sI[i] = 0.0f;
  }
  __syncthreads();

  // A-weights: wave-uniform -> SGPRs, then v2f splats over the basis pair
  float w[21];
  #pragma unroll
  for (int i = 0; i < 21; i++)
    w[i] = __uint_as_float(
        (unsigned)__builtin_amdgcn_readfirstlane(__float_as_uint(sAW[i])));
  Wp2 W;
  W.w0 = SP(w[0]);   W.w1 = SP(w[1]);   W.w2 = SP(w[2]);   W.w3 = SP(w[3]);
  W.w6 = SP(w[6]);   W.w7 = SP(w[7]);   W.w9 = SP(w[9]);   W.w10 = SP(w[10]);
  W.w13 = SP(w[13]); W.w14 = SP(w[14]); W.w15 = SP(w[15]); W.w16 = SP(w[16]);
  W.w17 = SP(w[17]); W.w18 = SP(w[18]);
  W.w4 = w[4]; W.w5 = w[5]; W.w8 = w[8]; W.w11 = w[11];

  // ---- scan ----
  const int t0 = chunk * CLEN;

  v2f Q[23];
  #pragma unroll
  for (int p = 0; p < 23; p++) {
    Q[p].x = (row16 == PERMC[p]) ? 1.0f : 0.0f;        // basis A = state row16
    Q[p].y = (row16 + 16 == PERMC[p]) ? 1.0f : 0.0f;   // basis B = row16+16
  }
  v2f L = (v2f){0.0f, 0.0f};

  v4f FA[6], FB[6];
  int c12, p2;
  int4 q0 = *(const int4*)(trow + t0);
  int4 q1 = *(const int4*)(trow + t0 + 4);

  int b = 0;
  if (chunk == 0) {
    // body 0 = steps t = 1..7 (t = 0 folded into the combine's init)
    c12 = 20 + q0.x; p2 = q0.x;
    LDROW(FA, q0.y);
    LDSTEP(FB, FA, q0.z);
    LDSTEP(FA, FB, q0.w);
    LDSTEP(FB, FA, q1.x);
    LDSTEP(FA, FB, q1.y);
    LDSTEP(FB, FA, q1.z);
    LDSTEP(FA, FB, q1.w);
    step_pk2(Q, FA, W);
    b = 1;
    q0 = *(const int4*)(trow + 8);
    q1 = *(const int4*)(trow + 12);
  } else {
    int2 pp = *(const int2*)(trow + t0 - 2);
    c12 = pp.x * 5 + pp.y; p2 = pp.y;
  }

  for (; b < CLEN / 8; b++) {
    int4 n0 = q0, n1 = q1;
    if (b + 1 < CLEN / 8) {               // distance-1 global token prefetch
      n0 = *(const int4*)(trow + t0 + (b + 1) * 8);
      n1 = *(const int4*)(trow + t0 + (b + 1) * 8 + 4);
    }
    LDROW(FA, q0.x);
    LDSTEP(FB, FA, q0.y);
    LDSTEP(FA, FB, q0.z);
    LDSTEP(FB, FA, q0.w);
    LDSTEP(FA, FB, q1.x);
    LDSTEP(FB, FA, q1.y);
    LDSTEP(FA, FB, q1.z);
    LDSTEP(FB, FA, q1.w);
    step_pk2(Q, FB, W);
    if (b & 1) renorm_pk2(Q, L);          // every 16 steps (x16 prescale)
    q0 = n0; q1 = n1;
  }

  // undo the x16 prescale exactly: chunk 0 ran 127 steps, others 128
  const float undo = (chunk == 0 ? 127.0f : 128.0f) * LOG16;
  if (L.x > -1.0e38f) L.x -= undo;
  if (L.y > -1.0e38f) L.y -= undo;

  // stash chunk matrix rows (bf16, PERMUTED position order) + fp32 L.
  // basis A = state row16 (always live); basis B = row16+16 (live if < 23).
  {
    const int baseA = (chunk * NLIVE + row16) * 24;
    #pragma unroll
    for (int k = 0; k < 12; k++) {
      ushort2 p;
      p.x = f2bf(Q[2 * k].x);
      p.y = (2 * k + 1 < 23) ? f2bf(Q[2 * k + 1].x) : (unsigned short)0;
      *(ushort2*)&sT[baseA + 2 * k] = p;
    }
    sL[chunk * NLIVE + row16] = L.x;
    if (row16 < 7) {
      const int baseB = (chunk * NLIVE + row16 + 16) * 24;
      #pragma unroll
      for (int k = 0; k < 12; k++) {
        ushort2 p;
        p.x = f2bf(Q[2 * k].y);
        p.y = (2 * k + 1 < 23) ? f2bf(Q[2 * k + 1].y) : (unsigned short)0;
        *(ushort2*)&sT[baseB + 2 * k] = p;
      }
      sL[chunk * NLIVE + row16 + 16] = L.y;
    }
  }
  __syncthreads();

  // ---- combine (wave 0): fold 16 chunk matrices; lane j = canonical col ----
  if (tid < 64) {
    const int lane = tid;
    const bool act = (lane < NLIVE);

    int jp = 23;                          // lane's PERMUTED position
    #pragma unroll
    for (int pos = 0; pos < 23; pos++)
      if (PERMC[pos] == lane) jp = pos;

    const int tok0 = trow[0];
    const int idx0 = 96 + tok0;           // packed (4,4,tok0)

    float v = act ? sI[lane] * sBt[idx0 * PITCH + jp] : 0.0f;
    float s = v;
    #pragma unroll
    for (int m = 1; m < 32; m <<= 1) s += __shfl_xor(s, m, 32);
    float ll = __logf(s) - LOG16;         // undo prescale on step 0
    v = act ? v * __fdividef(1.0f, s) : 0.0f;

    for (int c = 0; c < CHUNKS; c++) {
      float Lj  = act ? sL[c * NLIVE + lane] : -3.0e38f;
      float key = (act && v > 0.0f) ? Lj : -3.0e38f;
      float mx = key;
      #pragma unroll
      for (int m = 1; m < 32; m <<= 1) mx = fmaxf(mx, __shfl_xor(mx, m, 32));
      float wgt = (act && v > 0.0f) ? v * __expf(Lj - mx) : 0.0f;

      float nv = 0.0f;
      #pragma unroll
      for (int r = 0; r < NLIVE; r++) {
        float wr = __shfl(wgt, r, 64);
        nv += wr * __uint_as_float(((unsigned)sT[(c * NLIVE + r) * 24 + jp]) << 16);
      }
      float nva = act ? nv : 0.0f;
      float s2 = nva;
      #pragma unroll
      for (int m = 1; m < 32; m <<= 1) s2 += __shfl_xor(s2, m, 32);
      ll += mx + __logf(s2);
      v = act ? nv * __fdividef(1.0f, s2) : 0.0f;
    }

    if (lane == 0) out[seq] = ll;
  }
}

// ---------------------------------------------------------------------------
extern "C" void kernel_launch(void* const* d_in, const int* in_sizes, int n_in,
                              void* d_out, int out_size, void* d_ws, size_t ws_size,
                              hipStream_t stream) {
  const float* wT = (const float*)d_in[0];   // transition_kernel (10)
  const float* wE = (const float*)d_in[1];   // emission_kernel (5400)
  const float* wI = (const float*)d_in[2];   // init_kernel (25)
  const int* tokens = (const int*)d_in[3];   // (512, 2048) int32
  float* out = (float*)d_out;                // (512,) float32
  (void)d_ws; (void)ws_size;                 // workspace unused

  hmm_kernel<<<NSEQ, 256, 0, stream>>>(wT, wE, wI, tokens, out);
}